// Round 9
// baseline (41788.547 us; speedup 1.0000x reference)
//
#include <hip/hip_runtime.h>
#include <math.h>

// Problem constants (from reference)
#define T_STEPS 8192
#define INPUT   64
#define UNITS   1024
#define NMOD    4
#define LEAKY   0.9f

// Decomposition (validated R6/R7): 16 WGs per module; module = blockIdx%8
// (residues 0..3; 4..7 exit) so round-robin XCD dispatch puts each module's
// WGs on ONE XCD -> h exchange through that XCD's L2 (sc0 loads; R6 cut
// FETCH 2GB->124MB). Slow agent-scope (MALL) path backs it up so correctness
// holds for arbitrary placement.
//
// Transposed ownership (R7): lane l of EVERY wave owns column c = wgi*64+l.
// Wave w handles h-rows [64w,64w+64): polls those 64 packed {tag|h} entries,
// deposits them in a wave-private LDS slice, re-reads as 16 uniform-address
// float4 broadcasts, FMAs against its 64 weights. Partials go to LDS.
//
// NEW (R9): no per-step __syncthreads. Each wave release-increments an LDS
// counter after its partial write and goes straight to polling; wave 0
// acquire-spins on the counter, combines, publishes. Poll loop is fast-path
// dominant (sc0/L2 spin, MALL checked 1-in-24) with no s_sleep.
#define K_WG        16
#define COLS_PER_WG 64
#define GRID        128
#define WGSIZE      1024

#define ENTRIES     (NMOD * UNITS)   // 4096 packed entries per buffer
// d_ws layout: slow[2][ENTRIES] then fast[2][ENTRIES], 64-bit {tag|value}.
#define WS_ULL      (4 * ENTRIES)
#define FAST_TRIES  24

__global__ void init_ws_kernel(unsigned long long* __restrict__ b) {
    int i = blockIdx.x * blockDim.x + threadIdx.x;
    if (i < WS_ULL) b[i] = 0ULL;     // tag 0 < any t in 1..T
}

// tanh via exp2 + rcp: ~1e-6 rel err, correct saturation (verified R4).
__device__ __forceinline__ float tanh_fast(float x) {
    float e2x = __builtin_amdgcn_exp2f(x * 2.8853900817779268f); // 2*log2(e)
    float r   = __builtin_amdgcn_rcpf(e2x + 1.0f);
    return fmaf(-2.0f, r, 1.0f);
}

// L1-bypass (sc0) 8-byte load: served coherently from the LOCAL XCD's L2.
__device__ __forceinline__ unsigned long long load_l2(
        const unsigned long long* p) {
    unsigned long long v;
    asm volatile("global_load_dwordx2 %0, %1, off sc0\n\t"
                 "s_waitcnt vmcnt(0)"
                 : "=v"(v) : "v"(p) : "memory");
    return v;
}

__global__ __launch_bounds__(WGSIZE, 1)
void reservoir_persist(const float* __restrict__ u,
                       const float* __restrict__ kern,
                       const float* __restrict__ rec,
                       const float* __restrict__ bias,
                       float* __restrict__ out,
                       unsigned long long* __restrict__ slow,
                       unsigned long long* __restrict__ fast)
{
    const int wg  = blockIdx.x;
    const int res = wg & 7;
    if (res >= NMOD) return;             // residues 4..7 idle
    const int m   = res;                 // module 0..3
    const int wgi = wg >> 3;             // 0..15 within module

    const int tid  = threadIdx.x;
    const int w    = tid >> 6;           // wave 0..15  (row-slice owner)
    const int lane = tid & 63;

    const int c       = wgi * COLS_PER_WG + lane;  // my column (module-local)
    const int rowBase = 64 * w;                    // my wave's h-row slice

    __shared__ __align__(16) float h_slice[16][64]; // wave-private row slices
    __shared__ float part[2][16][64];               // double-buffered partials
    __shared__ unsigned int cnt[2];                 // partial-arrival counters

    // ---- one-time preload of weights into registers ----
    const float* recm = rec + (size_t)m * UNITS * UNITS;
    float r[64];
#pragma unroll
    for (int j = 0; j < 16; ++j)
#pragma unroll
        for (int e = 0; e < 4; ++e)
            r[4 * j + e] = recm[(size_t)(rowBase + 4 * j + e) * UNITS + c];
#pragma unroll
    for (int j = 0; j < 64; ++j) asm volatile("" : "+v"(r[j]));

    // input kernel slice: wave w folds u-rows [4w, 4w+4)
    const float* km = kern + (size_t)m * INPUT * UNITS;
    const float k0 = km[(size_t)(4 * w + 0) * UNITS + c];
    const float k1 = km[(size_t)(4 * w + 1) * UNITS + c];
    const float k2 = km[(size_t)(4 * w + 2) * UNITS + c];
    const float k3 = km[(size_t)(4 * w + 3) * UNITS + c];
    const float bc = bias[m * UNITS + c];

    const float leak = LEAKY, omleak = 1.0f - LEAKY;

    h_slice[w][lane] = 0.0f;             // h_0 = 0 (wave-private slice)
    if (tid < 2) cnt[tid] = 0u;
    float hprev = 0.0f;                  // wave 0: my column's h state
    __syncthreads();                     // the only barrier

    const size_t modOff = (size_t)m * UNITS;

    // u quad for step 1 (uses u[0]); uniform per wave
    float4 uq = *reinterpret_cast<const float4*>(u + 4 * w);

    for (int t = 1; t <= T_STEPS; ++t) {
        const int pb = t & 1;

        // ---- FMA phase: rows [64w,64w+64) x my column, h via LDS broadcast
        const float4* __restrict__ hs4 =
            reinterpret_cast<const float4*>(h_slice[w]);
        float a0 = uq.x * k0, a1 = uq.y * k1, a2 = uq.z * k2, a3 = uq.w * k3;
#pragma unroll
        for (int j = 0; j < 16; ++j) {
            float4 hv4 = hs4[j];         // uniform address -> HW broadcast
            a0 = fmaf(r[4 * j + 0], hv4.x, a0);
            a1 = fmaf(r[4 * j + 1], hv4.y, a1);
            a2 = fmaf(r[4 * j + 2], hv4.z, a2);
            a3 = fmaf(r[4 * j + 3], hv4.w, a3);
        }
        part[pb][w][lane] = (a0 + a1) + (a2 + a3);
        // Release-increment: orders this wave's part ds_write before the add
        // (compiler emits lgkmcnt drain). Waves then proceed to poll -- no
        // barrier, so nobody waits on straggler waves except wave 0.
        if (lane == 0)
            __hip_atomic_fetch_add(&cnt[pb], 1u, __ATOMIC_RELEASE,
                                   __HIP_MEMORY_SCOPE_WORKGROUP);

        unsigned long long* fbW = fast + (size_t)pb * ENTRIES + modOff;
        unsigned long long* sbW = slow + (size_t)pb * ENTRIES + modOff;

        // ---- combine + publish (wave 0; lane l -> column c) ----
        // cnt[pb] is monotonic; the n-th use (n = (t+pb)/2... derived below)
        // completes when it reaches 16n: no reset, no wraparound (max 65536).
        // part[pb] reuse at t+2 is race-free: wave w's t+2 part-write needs
        // its (t+1)-poll, which needs every WG's (t+1)-publish, which (in
        // that WG's wave 0) is program-ordered after its t-combine reads.
        if (w == 0) {
            const unsigned tgt = 16u * (unsigned)((t + pb) >> 1);
            while (__hip_atomic_load(&cnt[pb], __ATOMIC_ACQUIRE,
                                     __HIP_MEMORY_SCOPE_WORKGROUP) < tgt) {}
            float s0 = part[pb][0][lane] + part[pb][1][lane];
            float s1 = part[pb][2][lane] + part[pb][3][lane];
            float s2 = part[pb][4][lane] + part[pb][5][lane];
            float s3 = part[pb][6][lane] + part[pb][7][lane];
#pragma unroll
            for (int ww = 8; ww < 16; ww += 4) {
                s0 += part[pb][ww][lane];     s1 += part[pb][ww + 1][lane];
                s2 += part[pb][ww + 2][lane]; s3 += part[pb][ww + 3][lane];
            }
            float s = (s0 + s1) + (s2 + s3);
            float hn = omleak * hprev + leak * tanh_fast(s + bc);
            hprev = hn;
            unsigned long long pk =
                ((unsigned long long)(unsigned int)t << 32) |
                (unsigned long long)__float_as_uint(hn);
            // fast: plain store -> local XCD L2 (visible to sc0 loads there)
            __hip_atomic_store(&fbW[c], pk, __ATOMIC_RELAXED,
                               __HIP_MEMORY_SCOPE_WORKGROUP);
            // slow: agent store -> MALL (correct for any WG placement)
            __hip_atomic_store(&sbW[c], pk, __ATOMIC_RELAXED,
                               __HIP_MEMORY_SCOPE_AGENT);
        }

        // prefetch next u quad (latency overlaps the poll)
        if (t < T_STEPS)
            uq = *reinterpret_cast<const float4*>(u + (size_t)t * INPUT + 4 * w);

        // ---- poll my row slice (entry tid = 64w+lane): fast-dominant ----
        unsigned long long v;
        int tries = 0;
        for (;;) {
            v = load_l2(&fbW[tid]);
            if ((unsigned int)(v >> 32) == (unsigned int)t) break;
            if (++tries >= FAST_TRIES) {      // rare MALL fallback
                v = __hip_atomic_load(&sbW[tid], __ATOMIC_RELAXED,
                                      __HIP_MEMORY_SCOPE_AGENT);
                if ((unsigned int)(v >> 32) == (unsigned int)t) break;
                tries = 0;
            }
        }
        const float hv = __uint_as_float((unsigned int)v);
        h_slice[w][lane] = hv;           // wave-private; in-wave ds ordering

        // one WG per module writes the coalesced output row (off crit path)
        if (wgi == 0)
            out[(size_t)(t - 1) * (NMOD * UNITS) + modOff + tid] = hv;
    }
}

extern "C" void kernel_launch(void* const* d_in, const int* in_sizes, int n_in,
                              void* d_out, int out_size, void* d_ws, size_t ws_size,
                              hipStream_t stream) {
    const float* u    = (const float*)d_in[0];  // [1, 8192, 64]
    const float* kern = (const float*)d_in[1];  // [4, 64, 1024]
    const float* rec  = (const float*)d_in[2];  // [4, 1024, 1024]
    const float* bias = (const float*)d_in[3];  // [4, 1024]
    float* out = (float*)d_out;                 // [1, 8192, 4096] f32

    unsigned long long* slow = (unsigned long long*)d_ws;              // 64 KB
    unsigned long long* fast = slow + 2 * ENTRIES;                     // 64 KB

    hipLaunchKernelGGL(init_ws_kernel, dim3((WS_ULL + 1023) / 1024), dim3(1024),
                       0, stream, slow);

    void* args[] = { (void*)&u, (void*)&kern, (void*)&rec, (void*)&bias,
                     (void*)&out, (void*)&slow, (void*)&fast };
    hipLaunchCooperativeKernel((const void*)reservoir_persist,
                               dim3(GRID), dim3(WGSIZE), args, 0, stream);
}

// Round 10
// 29637.454 us; speedup vs baseline: 1.4100x; 1.4100x over previous
//
#include <hip/hip_runtime.h>
#include <math.h>

// Problem constants (from reference)
#define T_STEPS 8192
#define INPUT   64
#define UNITS   1024
#define NMOD    4
#define LEAKY   0.9f

// Decomposition (validated R6/R7): 16 WGs per module; module = blockIdx%8
// (residues 0..3; 4..7 exit) so round-robin XCD dispatch puts each module's
// WGs on ONE XCD -> h exchange through that XCD's L2 (sc0 loads; R6 cut
// FETCH 2GB->124MB). Slow agent-scope (MALL) path backs it up so correctness
// holds for arbitrary WG placement.
//
// Transposed ownership (R7): lane l of EVERY wave owns column c = wgi*64+l.
// Wave w handles h-rows [64w,64w+64): polls those 64 packed {tag|h} entries
// (exactly WG w's publish), deposits them in a wave-private LDS slice,
// re-reads as 16 uniform-address float4 broadcasts, FMAs against 64 weights.
// Partials combine in LDS after ONE barrier; wave 0 finishes + publishes.
//
// R9 lesson (and R5): the per-step __syncthreads is LOAD-BEARING. Barrier-
// free dataflow convoys catastrophically (41-102ms). Keep lockstep.
// R10: poll loop is fast-path dominant -- spin on the ~250cy L2 load, check
// MALL only 1-in-16 misses, no s_sleep (R8 showed sleep hurts).
#define K_WG        16
#define COLS_PER_WG 64
#define GRID        128
#define WGSIZE      1024

#define ENTRIES     (NMOD * UNITS)   // 4096 packed entries per buffer
// d_ws layout: slow[2][ENTRIES] then fast[2][ENTRIES], 64-bit {tag|value}.
#define WS_ULL      (4 * ENTRIES)
#define FAST_TRIES  16

__global__ void init_ws_kernel(unsigned long long* __restrict__ b) {
    int i = blockIdx.x * blockDim.x + threadIdx.x;
    if (i < WS_ULL) b[i] = 0ULL;     // tag 0 < any t in 1..T
}

// tanh via exp2 + rcp: ~1e-6 rel err, correct saturation (verified R4).
__device__ __forceinline__ float tanh_fast(float x) {
    float e2x = __builtin_amdgcn_exp2f(x * 2.8853900817779268f); // 2*log2(e)
    float r   = __builtin_amdgcn_rcpf(e2x + 1.0f);
    return fmaf(-2.0f, r, 1.0f);
}

// L1-bypass (sc0) 8-byte load: served coherently from the LOCAL XCD's L2.
__device__ __forceinline__ unsigned long long load_l2(
        const unsigned long long* p) {
    unsigned long long v;
    asm volatile("global_load_dwordx2 %0, %1, off sc0\n\t"
                 "s_waitcnt vmcnt(0)"
                 : "=v"(v) : "v"(p) : "memory");
    return v;
}

__global__ __launch_bounds__(WGSIZE, 1)
void reservoir_persist(const float* __restrict__ u,
                       const float* __restrict__ kern,
                       const float* __restrict__ rec,
                       const float* __restrict__ bias,
                       float* __restrict__ out,
                       unsigned long long* __restrict__ slow,
                       unsigned long long* __restrict__ fast)
{
    const int wg  = blockIdx.x;
    const int res = wg & 7;
    if (res >= NMOD) return;             // residues 4..7 idle
    const int m   = res;                 // module 0..3
    const int wgi = wg >> 3;             // 0..15 within module

    const int tid  = threadIdx.x;
    const int w    = tid >> 6;           // wave 0..15  (row-slice owner)
    const int lane = tid & 63;

    const int c       = wgi * COLS_PER_WG + lane;  // my column (module-local)
    const int rowBase = 64 * w;                    // my wave's h-row slice

    __shared__ __align__(16) float h_slice[16][64]; // wave-private row slices
    __shared__ float part[2][16][64];               // double-buffered partials

    // ---- one-time preload of weights into registers ----
    const float* recm = rec + (size_t)m * UNITS * UNITS;
    float r[64];
#pragma unroll
    for (int j = 0; j < 16; ++j)
#pragma unroll
        for (int e = 0; e < 4; ++e)
            r[4 * j + e] = recm[(size_t)(rowBase + 4 * j + e) * UNITS + c];
#pragma unroll
    for (int j = 0; j < 64; ++j) asm volatile("" : "+v"(r[j]));

    // input kernel slice: wave w folds u-rows [4w, 4w+4)
    const float* km = kern + (size_t)m * INPUT * UNITS;
    const float k0 = km[(size_t)(4 * w + 0) * UNITS + c];
    const float k1 = km[(size_t)(4 * w + 1) * UNITS + c];
    const float k2 = km[(size_t)(4 * w + 2) * UNITS + c];
    const float k3 = km[(size_t)(4 * w + 3) * UNITS + c];
    const float bc = bias[m * UNITS + c];

    const float leak = LEAKY, omleak = 1.0f - LEAKY;

    h_slice[w][lane] = 0.0f;             // h_0 = 0 (wave-private slice)
    float hprev = 0.0f;                  // wave 0: my column's h state
    __syncthreads();

    const size_t modOff = (size_t)m * UNITS;

    // u quad for step 1 (uses u[0]); uniform per wave
    float4 uq = *reinterpret_cast<const float4*>(u + 4 * w);

    for (int t = 1; t <= T_STEPS; ++t) {
        const int pb = t & 1;

        // ---- FMA phase: rows [64w,64w+64) x my column, h via LDS broadcast
        const float4* __restrict__ hs4 =
            reinterpret_cast<const float4*>(h_slice[w]);
        float a0 = uq.x * k0, a1 = uq.y * k1, a2 = uq.z * k2, a3 = uq.w * k3;
#pragma unroll
        for (int j = 0; j < 16; ++j) {
            float4 hv4 = hs4[j];         // uniform address -> HW broadcast
            a0 = fmaf(r[4 * j + 0], hv4.x, a0);
            a1 = fmaf(r[4 * j + 1], hv4.y, a1);
            a2 = fmaf(r[4 * j + 2], hv4.z, a2);
            a3 = fmaf(r[4 * j + 3], hv4.w, a3);
        }
        part[pb][w][lane] = (a0 + a1) + (a2 + a3);
        __syncthreads();   // partials of step t visible; only barrier/step

        unsigned long long* fbW = fast + (size_t)pb * ENTRIES + modOff;
        unsigned long long* sbW = slow + (size_t)pb * ENTRIES + modOff;

        // ---- combine + publish (wave 0; lane l -> column c) ----
        // part[pb] reuse (next write at t+2) is race-free: wave w's
        // part[pb] write at t+2 requires its (t+1)-poll, which requires
        // every WG's (t+1)-publish, which is program-ordered (in that WG's
        // wave 0) after its t-combine reads here.
        if (w == 0) {
            float s0 = part[pb][0][lane] + part[pb][1][lane];
            float s1 = part[pb][2][lane] + part[pb][3][lane];
            float s2 = part[pb][4][lane] + part[pb][5][lane];
            float s3 = part[pb][6][lane] + part[pb][7][lane];
#pragma unroll
            for (int ww = 8; ww < 16; ww += 4) {
                s0 += part[pb][ww][lane];     s1 += part[pb][ww + 1][lane];
                s2 += part[pb][ww + 2][lane]; s3 += part[pb][ww + 3][lane];
            }
            float s = (s0 + s1) + (s2 + s3);
            float hn = omleak * hprev + leak * tanh_fast(s + bc);
            hprev = hn;
            unsigned long long pk =
                ((unsigned long long)(unsigned int)t << 32) |
                (unsigned long long)__float_as_uint(hn);
            // fast: plain store -> local XCD L2 (visible to sc0 loads there)
            __hip_atomic_store(&fbW[c], pk, __ATOMIC_RELAXED,
                               __HIP_MEMORY_SCOPE_WORKGROUP);
            // slow: agent store -> MALL (correct for any WG placement)
            __hip_atomic_store(&sbW[c], pk, __ATOMIC_RELAXED,
                               __HIP_MEMORY_SCOPE_AGENT);
        }

        // prefetch next u quad (latency overlaps the poll)
        if (t < T_STEPS)
            uq = *reinterpret_cast<const float4*>(u + (size_t)t * INPUT + 4 * w);

        // ---- poll my row slice (entry tid = 64w+lane): fast-dominant ----
        // Spin on the ~250cy L2 load; MALL fallback only 1-in-16 misses
        // (guarantees progress for arbitrary WG->XCD placement). No sleep.
        unsigned long long v;
        int tries = 0;
        for (;;) {
            v = load_l2(&fbW[tid]);
            if ((unsigned int)(v >> 32) == (unsigned int)t) break;
            if (__builtin_expect(++tries >= FAST_TRIES, 0)) {
                v = __hip_atomic_load(&sbW[tid], __ATOMIC_RELAXED,
                                      __HIP_MEMORY_SCOPE_AGENT);
                if ((unsigned int)(v >> 32) == (unsigned int)t) break;
                tries = 0;
            }
        }
        const float hv = __uint_as_float((unsigned int)v);
        h_slice[w][lane] = hv;           // wave-private; in-wave ds ordering

        // one WG per module writes the coalesced output row (off crit path)
        if (wgi == 0)
            out[(size_t)(t - 1) * (NMOD * UNITS) + modOff + tid] = hv;
    }
}

extern "C" void kernel_launch(void* const* d_in, const int* in_sizes, int n_in,
                              void* d_out, int out_size, void* d_ws, size_t ws_size,
                              hipStream_t stream) {
    const float* u    = (const float*)d_in[0];  // [1, 8192, 64]
    const float* kern = (const float*)d_in[1];  // [4, 64, 1024]
    const float* rec  = (const float*)d_in[2];  // [4, 1024, 1024]
    const float* bias = (const float*)d_in[3];  // [4, 1024]
    float* out = (float*)d_out;                 // [1, 8192, 4096] f32

    unsigned long long* slow = (unsigned long long*)d_ws;              // 64 KB
    unsigned long long* fast = slow + 2 * ENTRIES;                     // 64 KB

    hipLaunchKernelGGL(init_ws_kernel, dim3((WS_ULL + 1023) / 1024), dim3(1024),
                       0, stream, slow);

    void* args[] = { (void*)&u, (void*)&kern, (void*)&rec, (void*)&bias,
                     (void*)&out, (void*)&slow, (void*)&fast };
    hipLaunchCooperativeKernel((const void*)reservoir_persist,
                               dim3(GRID), dim3(WGSIZE), args, 0, stream);
}

// Round 11
// 25830.331 us; speedup vs baseline: 1.6178x; 1.1474x over previous
//
#include <hip/hip_runtime.h>
#include <math.h>

// Problem constants (from reference)
#define T_STEPS 8192
#define INPUT   64
#define UNITS   1024
#define NMOD    4
#define LEAKY   0.9f

// Decomposition (validated R6/R7): 16 WGs per module; module = blockIdx%8
// (residues 0..3; 4..7 exit) so round-robin XCD dispatch puts each module's
// WGs on ONE XCD -> h exchange through that XCD's L2 (sc0 loads; R6 cut
// FETCH 2GB->124MB). Agent-scope (MALL) path backs everything up so
// correctness holds for arbitrary WG placement.
//
// Transposed ownership (R7): lane l of EVERY wave owns column c = wgi*64+l.
// Wave w handles h-rows [64w,64w+64): it consumes exactly WG w's publish,
// deposits it in a wave-private LDS slice, re-reads as 16 uniform-address
// float4 broadcasts, FMAs against 64 weights. Partials combine in LDS after
// ONE barrier; wave 0 finishes (bias+tanh+blend) and publishes.
//
// Hard-won rules: per-step __syncthreads is LOAD-BEARING (R5/R9: removal ->
// 2-7x convoy collapse). Aggregate sc0-poll pressure kills the L2 (R10:
// fast-dominant polling by all 16 waves -> 2.2x slower).
//
// NEW (R11): single-poller topology. Publishers also write a 16-word
// per-module DONE vector. Wave 15 of each WG (idle during wave 0's combine)
// polls ONLY the done vector (1-2 lines); waves 0-14 spin on an LDS go-flag
// (zero L2 traffic). After go, each wave issues a single-shot sc0 load of
// its 64 data entries and TAG-VERIFIES them (done is just a hint; the
// {tag|value} packing keeps correctness fence-free). L2 poll pressure drops
// 16x while detection stays ~250cy granular.
#define K_WG        16
#define COLS_PER_WG 64
#define GRID        128
#define WGSIZE      1024

#define ENTRIES     (NMOD * UNITS)   // 4096 packed entries per buffer
// d_ws layout (ULLs): slow[2][ENTRIES] | fast[2][ENTRIES] |
//                     sdone[2][NMOD][16] | fdone[2][NMOD][16]
#define SDONE_OFF   (4 * ENTRIES)
#define FDONE_OFF   (4 * ENTRIES + 2 * NMOD * 16)
#define WS_ULL      (4 * ENTRIES + 4 * NMOD * 16)

__global__ void init_ws_kernel(unsigned long long* __restrict__ b) {
    int i = blockIdx.x * blockDim.x + threadIdx.x;
    if (i < WS_ULL) b[i] = 0ULL;     // tag 0 < any t in 1..T
}

// tanh via exp2 + rcp: ~1e-6 rel err, correct saturation (verified R4).
__device__ __forceinline__ float tanh_fast(float x) {
    float e2x = __builtin_amdgcn_exp2f(x * 2.8853900817779268f); // 2*log2(e)
    float r   = __builtin_amdgcn_rcpf(e2x + 1.0f);
    return fmaf(-2.0f, r, 1.0f);
}

// L1-bypass (sc0) 8-byte load: served coherently from the LOCAL XCD's L2.
__device__ __forceinline__ unsigned long long load_l2(
        const unsigned long long* p) {
    unsigned long long v;
    asm volatile("global_load_dwordx2 %0, %1, off sc0\n\t"
                 "s_waitcnt vmcnt(0)"
                 : "=v"(v) : "v"(p) : "memory");
    return v;
}

__global__ __launch_bounds__(WGSIZE, 1)
void reservoir_persist(const float* __restrict__ u,
                       const float* __restrict__ kern,
                       const float* __restrict__ rec,
                       const float* __restrict__ bias,
                       float* __restrict__ out,
                       unsigned long long* __restrict__ ws)
{
    unsigned long long* __restrict__ slow  = ws;
    unsigned long long* __restrict__ fast  = ws + 2 * ENTRIES;
    unsigned long long* __restrict__ sdone = ws + SDONE_OFF;
    unsigned long long* __restrict__ fdone = ws + FDONE_OFF;

    const int wg  = blockIdx.x;
    const int res = wg & 7;
    if (res >= NMOD) return;             // residues 4..7 idle
    const int m   = res;                 // module 0..3
    const int wgi = wg >> 3;             // 0..15 within module

    const int tid  = threadIdx.x;
    const int w    = tid >> 6;           // wave 0..15  (row-slice owner)
    const int lane = tid & 63;

    const int c       = wgi * COLS_PER_WG + lane;  // my column (module-local)
    const int rowBase = 64 * w;                    // my wave's h-row slice

    __shared__ __align__(16) float h_slice[16][64]; // wave-private row slices
    __shared__ float part[2][16][64];               // double-buffered partials
    __shared__ unsigned int go[2];                  // LDS go-flags (by parity)

    // ---- one-time preload of weights into registers ----
    const float* recm = rec + (size_t)m * UNITS * UNITS;
    float r[64];
#pragma unroll
    for (int j = 0; j < 16; ++j)
#pragma unroll
        for (int e = 0; e < 4; ++e)
            r[4 * j + e] = recm[(size_t)(rowBase + 4 * j + e) * UNITS + c];
#pragma unroll
    for (int j = 0; j < 64; ++j) asm volatile("" : "+v"(r[j]));

    // input kernel slice: wave w folds u-rows [4w, 4w+4)
    const float* km = kern + (size_t)m * INPUT * UNITS;
    const float k0 = km[(size_t)(4 * w + 0) * UNITS + c];
    const float k1 = km[(size_t)(4 * w + 1) * UNITS + c];
    const float k2 = km[(size_t)(4 * w + 2) * UNITS + c];
    const float k3 = km[(size_t)(4 * w + 3) * UNITS + c];
    const float bc = bias[m * UNITS + c];

    const float leak = LEAKY, omleak = 1.0f - LEAKY;

    h_slice[w][lane] = 0.0f;             // h_0 = 0 (wave-private slice)
    if (tid < 2) go[tid] = 0u;
    float hprev = 0.0f;                  // wave 0: my column's h state
    __syncthreads();

    const size_t modOff = (size_t)m * UNITS;

    // u quad for step 1 (uses u[0]); uniform per wave
    float4 uq = *reinterpret_cast<const float4*>(u + 4 * w);

    for (int t = 1; t <= T_STEPS; ++t) {
        const int pb = t & 1;

        // ---- FMA phase: rows [64w,64w+64) x my column, h via LDS broadcast
        const float4* __restrict__ hs4 =
            reinterpret_cast<const float4*>(h_slice[w]);
        float a0 = uq.x * k0, a1 = uq.y * k1, a2 = uq.z * k2, a3 = uq.w * k3;
#pragma unroll
        for (int j = 0; j < 16; ++j) {
            float4 hv4 = hs4[j];         // uniform address -> HW broadcast
            a0 = fmaf(r[4 * j + 0], hv4.x, a0);
            a1 = fmaf(r[4 * j + 1], hv4.y, a1);
            a2 = fmaf(r[4 * j + 2], hv4.z, a2);
            a3 = fmaf(r[4 * j + 3], hv4.w, a3);
        }
        part[pb][w][lane] = (a0 + a1) + (a2 + a3);
        __syncthreads();   // partials of step t visible; only barrier/step

        unsigned long long* fbW = fast + (size_t)pb * ENTRIES + modOff;
        unsigned long long* sbW = slow + (size_t)pb * ENTRIES + modOff;
        unsigned long long* fdW = fdone + ((size_t)pb * NMOD + m) * 16;
        unsigned long long* sdW = sdone + ((size_t)pb * NMOD + m) * 16;

        // ---- combine + publish (wave 0; lane l -> column c) ----
        // part[pb] reuse at t+2 is race-free: wave w's t+2 part-write needs
        // its (t+1) go/data, which needs every WG's (t+1)-publish, which is
        // program-ordered (in that WG's wave 0) after its t-combine reads.
        if (w == 0) {
            float s0 = part[pb][0][lane] + part[pb][1][lane];
            float s1 = part[pb][2][lane] + part[pb][3][lane];
            float s2 = part[pb][4][lane] + part[pb][5][lane];
            float s3 = part[pb][6][lane] + part[pb][7][lane];
#pragma unroll
            for (int ww = 8; ww < 16; ww += 4) {
                s0 += part[pb][ww][lane];     s1 += part[pb][ww + 1][lane];
                s2 += part[pb][ww + 2][lane]; s3 += part[pb][ww + 3][lane];
            }
            float s = (s0 + s1) + (s2 + s3);
            float hn = omleak * hprev + leak * tanh_fast(s + bc);
            hprev = hn;
            unsigned long long pk =
                ((unsigned long long)(unsigned int)t << 32) |
                (unsigned long long)__float_as_uint(hn);
            // data first (program order), then done hint
            __hip_atomic_store(&fbW[c], pk, __ATOMIC_RELAXED,
                               __HIP_MEMORY_SCOPE_WORKGROUP);
            __hip_atomic_store(&sbW[c], pk, __ATOMIC_RELAXED,
                               __HIP_MEMORY_SCOPE_AGENT);
            if (lane == 0) {
                unsigned long long dk =
                    ((unsigned long long)(unsigned int)t << 32) |
                    (unsigned int)wgi;
                __hip_atomic_store(&fdW[wgi], dk, __ATOMIC_RELAXED,
                                   __HIP_MEMORY_SCOPE_WORKGROUP);
                __hip_atomic_store(&sdW[wgi], dk, __ATOMIC_RELAXED,
                                   __HIP_MEMORY_SCOPE_AGENT);
            }
        }

        // prefetch next u quad (latency overlaps the wait)
        if (t < T_STEPS)
            uq = *reinterpret_cast<const float4*>(u + (size_t)t * INPUT + 4 * w);

        // ---- detection: wave 15 polls the 16-word done vector; the rest
        //      spin on the LDS go-flag (zero L2 traffic) ----
        // Within buffer pb, done/data tags can only be {t-2, t} while step-t
        // consumers wait (any t+2 publish transitively requires OUR t
        // consumption), so >= t detection is exact and deadlock-free.
        if (w == 15) {
            const int idx = lane & 15;   // 4x-replicated: same 1-2 lines
            int tries = 0;
            for (;;) {
                unsigned long long dv = load_l2(&fdW[idx]);
                if (__all((int)((unsigned int)(dv >> 32) >= (unsigned int)t)))
                    break;
                if (++tries >= 6) {      // MALL fallback (arbitrary placement)
                    dv = __hip_atomic_load(&sdW[idx], __ATOMIC_RELAXED,
                                           __HIP_MEMORY_SCOPE_AGENT);
                    if (__all((int)((unsigned int)(dv >> 32) >=
                                    (unsigned int)t)))
                        break;
                    tries = 0;
                }
            }
            if (lane == 0)
                __hip_atomic_store(&go[pb], (unsigned int)t, __ATOMIC_RELEASE,
                                   __HIP_MEMORY_SCOPE_WORKGROUP);
        } else {
            while (__hip_atomic_load(&go[pb], __ATOMIC_ACQUIRE,
                                     __HIP_MEMORY_SCOPE_WORKGROUP)
                   != (unsigned int)t) {}
        }

        // ---- single-shot data load (entry tid = 64w+lane), tag-verified ---
        unsigned long long v;
        int tries = 0;
        for (;;) {
            v = load_l2(&fbW[tid]);
            if ((unsigned int)(v >> 32) == (unsigned int)t) break;
            if (++tries >= 8) {          // rare: ordering slip or bad placement
                v = __hip_atomic_load(&sbW[tid], __ATOMIC_RELAXED,
                                      __HIP_MEMORY_SCOPE_AGENT);
                if ((unsigned int)(v >> 32) == (unsigned int)t) break;
                tries = 0;
            }
        }
        const float hv = __uint_as_float((unsigned int)v);
        h_slice[w][lane] = hv;           // wave-private; in-wave ds ordering

        // one WG per module writes the coalesced output row (off crit path)
        if (wgi == 0)
            out[(size_t)(t - 1) * (NMOD * UNITS) + modOff + tid] = hv;
    }
}

extern "C" void kernel_launch(void* const* d_in, const int* in_sizes, int n_in,
                              void* d_out, int out_size, void* d_ws, size_t ws_size,
                              hipStream_t stream) {
    const float* u    = (const float*)d_in[0];  // [1, 8192, 64]
    const float* kern = (const float*)d_in[1];  // [4, 64, 1024]
    const float* rec  = (const float*)d_in[2];  // [4, 1024, 1024]
    const float* bias = (const float*)d_in[3];  // [4, 1024]
    float* out = (float*)d_out;                 // [1, 8192, 4096] f32
    unsigned long long* ws = (unsigned long long*)d_ws;  // ~130 KB used

    hipLaunchKernelGGL(init_ws_kernel, dim3((WS_ULL + 1023) / 1024), dim3(1024),
                       0, stream, ws);

    void* args[] = { (void*)&u, (void*)&kern, (void*)&rec, (void*)&bias,
                     (void*)&out, (void*)&ws };
    hipLaunchCooperativeKernel((const void*)reservoir_persist,
                               dim3(GRID), dim3(WGSIZE), args, 0, stream);
}

// Round 12
// 16073.021 us; speedup vs baseline: 2.5999x; 1.6071x over previous
//
#include <hip/hip_runtime.h>
#include <math.h>

// Problem constants (from reference)
#define T_STEPS 8192
#define INPUT   64
#define UNITS   1024
#define NMOD    4
#define LEAKY   0.9f

// Decomposition: 16 WGs per module; module = blockIdx%8 residues 0..3
// (4..7 exit). WG = 1024 threads = 16 waves.
//
// Transposed ownership (R7, best-known 13.3ms): lane l of EVERY wave owns
// column c = wgi*64+l. Wave w handles h-rows [64w,64w+64): it polls exactly
// WG w's 64 packed {tag|h} entries, deposits them in a wave-private LDS
// slice, re-reads them as 16 uniform-address float4 broadcasts, and FMAs
// against 64 per-lane weights. Partials combine in LDS after ONE barrier;
// wave 0 finishes (bias + tanh + leaky blend) and publishes.
//
// Hard-won rules:
//  - per-step __syncthreads is LOAD-BEARING (R5/R9: removal -> 2-7x collapse)
//  - R7/R10/R11 triangulation: the sc0 "XCD-local L2 fast path" NEVER hits
//    under this cooperative launch (R10: 16 fast tries/slow -> 2.2x slower;
//    R11: fast-first done-vector -> 2x slower; both match all-fast-wasted
//    arithmetic). R12: agent/MALL path ONLY, tight single-load poll.
#define K_WG        16
#define COLS_PER_WG 64
#define GRID        128
#define WGSIZE      1024

#define ENTRIES     (NMOD * UNITS)   // 4096 packed entries per buffer
// d_ws layout: hb[2][ENTRIES] 64-bit {tag:32 | float:32}.
#define WS_ULL      (2 * ENTRIES)

__global__ void init_ws_kernel(unsigned long long* __restrict__ b) {
    int i = blockIdx.x * blockDim.x + threadIdx.x;
    if (i < WS_ULL) b[i] = 0ULL;     // tag 0 < any t in 1..T
}

// tanh via exp2 + rcp: ~1e-6 rel err, correct saturation (verified R4).
__device__ __forceinline__ float tanh_fast(float x) {
    float e2x = __builtin_amdgcn_exp2f(x * 2.8853900817779268f); // 2*log2(e)
    float r   = __builtin_amdgcn_rcpf(e2x + 1.0f);
    return fmaf(-2.0f, r, 1.0f);
}

__global__ __launch_bounds__(WGSIZE, 1)
void reservoir_persist(const float* __restrict__ u,
                       const float* __restrict__ kern,
                       const float* __restrict__ rec,
                       const float* __restrict__ bias,
                       float* __restrict__ out,
                       unsigned long long* __restrict__ hb)
{
    const int wg  = blockIdx.x;
    const int res = wg & 7;
    if (res >= NMOD) return;             // residues 4..7 idle
    const int m   = res;                 // module 0..3
    const int wgi = wg >> 3;             // 0..15 within module

    const int tid  = threadIdx.x;
    const int w    = tid >> 6;           // wave 0..15  (row-slice owner)
    const int lane = tid & 63;

    const int c       = wgi * COLS_PER_WG + lane;  // my column (module-local)
    const int rowBase = 64 * w;                    // my wave's h-row slice

    __shared__ __align__(16) float h_slice[16][64]; // wave-private row slices
    __shared__ float part[2][16][64];               // double-buffered partials

    // ---- one-time preload of weights into registers ----
    const float* recm = rec + (size_t)m * UNITS * UNITS;
    float r[64];
#pragma unroll
    for (int j = 0; j < 16; ++j)
#pragma unroll
        for (int e = 0; e < 4; ++e)
            r[4 * j + e] = recm[(size_t)(rowBase + 4 * j + e) * UNITS + c];
#pragma unroll
    for (int j = 0; j < 64; ++j) asm volatile("" : "+v"(r[j]));

    // input kernel slice: wave w folds u-rows [4w, 4w+4)
    const float* km = kern + (size_t)m * INPUT * UNITS;
    const float k0 = km[(size_t)(4 * w + 0) * UNITS + c];
    const float k1 = km[(size_t)(4 * w + 1) * UNITS + c];
    const float k2 = km[(size_t)(4 * w + 2) * UNITS + c];
    const float k3 = km[(size_t)(4 * w + 3) * UNITS + c];
    const float bc = bias[m * UNITS + c];

    const float leak = LEAKY, omleak = 1.0f - LEAKY;

    h_slice[w][lane] = 0.0f;             // h_0 = 0 (wave-private slice)
    float hprev = 0.0f;                  // wave 0: my column's h state
    __syncthreads();

    const size_t modOff = (size_t)m * UNITS;

    // u quad for step 1 (uses u[0]); uniform per wave
    float4 uq = *reinterpret_cast<const float4*>(u + 4 * w);

    for (int t = 1; t <= T_STEPS; ++t) {
        const int pb = t & 1;

        // ---- FMA phase: rows [64w,64w+64) x my column, h via LDS broadcast
        const float4* __restrict__ hs4 =
            reinterpret_cast<const float4*>(h_slice[w]);
        float a0 = uq.x * k0, a1 = uq.y * k1, a2 = uq.z * k2, a3 = uq.w * k3;
#pragma unroll
        for (int j = 0; j < 16; ++j) {
            float4 hv4 = hs4[j];         // uniform address -> HW broadcast
            a0 = fmaf(r[4 * j + 0], hv4.x, a0);
            a1 = fmaf(r[4 * j + 1], hv4.y, a1);
            a2 = fmaf(r[4 * j + 2], hv4.z, a2);
            a3 = fmaf(r[4 * j + 3], hv4.w, a3);
        }
        part[pb][w][lane] = (a0 + a1) + (a2 + a3);
        __syncthreads();   // partials of step t visible; only barrier/step

        unsigned long long* hbW = hb + (size_t)pb * ENTRIES + modOff;

        // ---- combine + publish (wave 0; lane l -> column c) ----
        // part[pb] reuse (next write at t+2) is race-free: wave w's
        // part[pb] write at t+2 requires its (t+1)-poll, which requires
        // every WG's (t+1)-publish, which is program-ordered (in that WG's
        // wave 0) after its t-combine reads here.
        if (w == 0) {
            float s0 = part[pb][0][lane] + part[pb][1][lane];
            float s1 = part[pb][2][lane] + part[pb][3][lane];
            float s2 = part[pb][4][lane] + part[pb][5][lane];
            float s3 = part[pb][6][lane] + part[pb][7][lane];
#pragma unroll
            for (int ww = 8; ww < 16; ww += 4) {
                s0 += part[pb][ww][lane];     s1 += part[pb][ww + 1][lane];
                s2 += part[pb][ww + 2][lane]; s3 += part[pb][ww + 3][lane];
            }
            float s = (s0 + s1) + (s2 + s3);
            float hn = omleak * hprev + leak * tanh_fast(s + bc);
            hprev = hn;
            unsigned long long pk =
                ((unsigned long long)(unsigned int)t << 32) |
                (unsigned long long)__float_as_uint(hn);
            // single agent-scope store -> device coherence point (MALL)
            __hip_atomic_store(&hbW[c], pk, __ATOMIC_RELAXED,
                               __HIP_MEMORY_SCOPE_AGENT);
        }

        // prefetch next u quad (latency overlaps the poll)
        if (t < T_STEPS)
            uq = *reinterpret_cast<const float4*>(u + (size_t)t * INPUT + 4 * w);

        // ---- poll my row slice (entry tid = 64w+lane) ----
        // Tight single-load agent-scope spin: period = one MALL RT (~800cy).
        // Tag+value share one 8B word, so a tag match delivers the value
        // atomically; double buffer (pb) makes tag-equality exact.
        unsigned long long v;
        for (;;) {
            v = __hip_atomic_load(&hbW[tid], __ATOMIC_RELAXED,
                                  __HIP_MEMORY_SCOPE_AGENT);
            if ((unsigned int)(v >> 32) == (unsigned int)t) break;
        }
        const float hv = __uint_as_float((unsigned int)v);
        h_slice[w][lane] = hv;           // wave-private; in-wave ds ordering

        // one WG per module writes the coalesced output row (off crit path)
        if (wgi == 0)
            out[(size_t)(t - 1) * (NMOD * UNITS) + modOff + tid] = hv;
    }
}

extern "C" void kernel_launch(void* const* d_in, const int* in_sizes, int n_in,
                              void* d_out, int out_size, void* d_ws, size_t ws_size,
                              hipStream_t stream) {
    const float* u    = (const float*)d_in[0];  // [1, 8192, 64]
    const float* kern = (const float*)d_in[1];  // [4, 64, 1024]
    const float* rec  = (const float*)d_in[2];  // [4, 1024, 1024]
    const float* bias = (const float*)d_in[3];  // [4, 1024]
    float* out = (float*)d_out;                 // [1, 8192, 4096] f32
    unsigned long long* hb = (unsigned long long*)d_ws;  // 64 KB packed h

    hipLaunchKernelGGL(init_ws_kernel, dim3((WS_ULL + 1023) / 1024), dim3(1024),
                       0, stream, hb);

    void* args[] = { (void*)&u, (void*)&kern, (void*)&rec, (void*)&bias,
                     (void*)&out, (void*)&hb };
    hipLaunchCooperativeKernel((const void*)reservoir_persist,
                               dim3(GRID), dim3(WGSIZE), args, 0, stream);
}